// Round 4
// baseline (750.614 us; speedup 1.0000x reference)
//
#include <hip/hip_runtime.h>

#define NN 100000
#define NE 1600000
#define SF 16
#define DF 32
#define EFT 8
#define HF 64

typedef __attribute__((ext_vector_type(8))) short short8;
typedef __attribute__((ext_vector_type(4))) float floatx4;

__device__ inline unsigned short f2bf(float f) {
  union { float f; unsigned int u; } v; v.f = f;
  unsigned int u = v.u + 0x7FFFu + ((v.u >> 16) & 1u);
  return (unsigned short)(u >> 16);
}
__device__ inline float bf2f(unsigned short h) {
  union { unsigned int u; float f; } v; v.u = ((unsigned int)h) << 16;
  return v.f;
}

// ---------------- CSR build ----------------
__global__ __launch_bounds__(256) void hist_kernel(const int* __restrict__ ei,
                                                   int* __restrict__ deg) {
  int e = blockIdx.x * 256 + threadIdx.x;
  if (e < NE) atomicAdd(&deg[ei[NE + e]], 1);
}

__global__ __launch_bounds__(256) void scan1_kernel(const int* __restrict__ deg,
                                                    int* __restrict__ cur,
                                                    int* __restrict__ bsums) {
  __shared__ int ts[256];
  int tid = threadIdx.x;
  int base = blockIdx.x * 1024 + tid * 4;
  int v[4];
#pragma unroll
  for (int q = 0; q < 4; ++q) v[q] = (base + q < NN) ? deg[base + q] : 0;
  int s = v[0] + v[1] + v[2] + v[3];
  ts[tid] = s;
  __syncthreads();
  for (int off = 1; off < 256; off <<= 1) {
    int t = (tid >= off) ? ts[tid - off] : 0;
    __syncthreads();
    ts[tid] += t;
    __syncthreads();
  }
  int excl = ts[tid] - s;
  if (tid == 255) bsums[blockIdx.x] = ts[255];
  int run = excl;
#pragma unroll
  for (int q = 0; q < 4; ++q) {
    if (base + q < NN) cur[base + q] = run;
    run += v[q];
  }
}

__global__ void scan2_kernel(int* __restrict__ bsums, int nb) {
  int acc = 0;
  for (int i = 0; i < nb; ++i) { int t = bsums[i]; bsums[i] = acc; acc += t; }
}

__global__ __launch_bounds__(256) void scan3_kernel(int* __restrict__ cur,
                                                    const int* __restrict__ bsums) {
  int i = blockIdx.x * 256 + threadIdx.x;
  if (i < NN) cur[i] += bsums[i >> 10];
}

__global__ __launch_bounds__(256) void fill_kernel(const int* __restrict__ ei,
                                                   const float* __restrict__ ea,
                                                   int* __restrict__ cur,
                                                   int* __restrict__ row_s,
                                                   int* __restrict__ col_s,
                                                   unsigned short* __restrict__ ea_s) {
  int e = blockIdx.x * 256 + threadIdx.x;
  if (e >= NE) return;
  int r = ei[e];
  int c = ei[NE + e];
  int pos = atomicAdd(&cur[c], 1);
  row_s[pos] = r;
  col_s[pos] = c;
  const float4* p = (const float4*)(ea + (size_t)e * EFT);
  float4 v0 = p[0], v1 = p[1];
  short8 ev;
  ev[0] = (short)f2bf(v0.x); ev[1] = (short)f2bf(v0.y);
  ev[2] = (short)f2bf(v0.z); ev[3] = (short)f2bf(v0.w);
  ev[4] = (short)f2bf(v1.x); ev[5] = (short)f2bf(v1.y);
  ev[6] = (short)f2bf(v1.z); ev[7] = (short)f2bf(v1.w);
  *(short8*)(ea_s + (size_t)pos * 8) = ev;
}

// ---------------- init: out = x_t @ F[0] ----------------
__global__ __launch_bounds__(256) void init_kernel(
    const float* __restrict__ x_t, const float* __restrict__ F0,
    float* __restrict__ out) {
  int n = blockIdx.x * 256 + threadIdx.x;
  if (n >= NN) return;
  float x[DF];
  const float4* xr = reinterpret_cast<const float4*>(x_t + (size_t)n * DF);
#pragma unroll
  for (int q = 0; q < 8; ++q) {
    float4 v = xr[q];
    x[4*q+0]=v.x; x[4*q+1]=v.y; x[4*q+2]=v.z; x[4*q+3]=v.w;
  }
  float4* orow = reinterpret_cast<float4*>(out + (size_t)n * DF);
#pragma unroll
  for (int q = 0; q < 8; ++q) {
    float4 acc = {0.f, 0.f, 0.f, 0.f};
#pragma unroll
    for (int i = 0; i < DF; ++i) {
      float xi = x[i];
      acc.x = fmaf(xi, F0[i*DF + 4*q+0], acc.x);
      acc.y = fmaf(xi, F0[i*DF + 4*q+1], acc.y);
      acc.z = fmaf(xi, F0[i*DF + 4*q+2], acc.z);
      acc.w = fmaf(xi, F0[i*DF + 4*q+3], acc.w);
    }
    orow[q] = acc;
  }
}

// ------- per-node precompute: A/B halves of layer-1 (bf16), outb, sums -------
__global__ __launch_bounds__(256) void pre_kernel(
    const float* __restrict__ x_s, const float* __restrict__ outp,
    const float* __restrict__ W1, unsigned short* __restrict__ ABh,
    unsigned short* __restrict__ outb, float* __restrict__ sums) {
  int n = blockIdx.x * 256 + threadIdx.x;
  if (n >= NN) return;
  float xs[SF];
  {
    const float4* p = (const float4*)(x_s + (size_t)n * SF);
#pragma unroll
    for (int q = 0; q < 4; ++q) {
      float4 v = p[q];
      xs[4*q]=v.x; xs[4*q+1]=v.y; xs[4*q+2]=v.z; xs[4*q+3]=v.w;
    }
  }
  float ot[DF];
  float s = 0.f;
  {
    const float4* p = (const float4*)(outp + (size_t)n * DF);
#pragma unroll
    for (int q = 0; q < 8; ++q) {
      float4 v = p[q];
      ot[4*q]=v.x; ot[4*q+1]=v.y; ot[4*q+2]=v.z; ot[4*q+3]=v.w;
      s += v.x + v.y + v.z + v.w;
    }
  }
  sums[n] = s;
  {
    unsigned short* ob = outb + (size_t)n * DF;
#pragma unroll
    for (int q = 0; q < 4; ++q) {
      short8 pk;
#pragma unroll
      for (int j = 0; j < 8; ++j) pk[j] = (short)f2bf(ot[q*8 + j]);
      *(short8*)(ob + q*8) = pk;
    }
  }
  unsigned short* abp = ABh + (size_t)n * 128;
  // A half (at +0): xs rows 0..15, out rows 32..63
#pragma unroll 1
  for (int ch = 0; ch < 4; ++ch) {
    float acc[16];
#pragma unroll
    for (int j = 0; j < 16; ++j) acc[j] = 0.f;
#pragma unroll
    for (int i = 0; i < SF; ++i) {
      float x = xs[i];
      const float* w = W1 + i * HF + ch * 16;
#pragma unroll
      for (int j = 0; j < 16; ++j) acc[j] = fmaf(x, w[j], acc[j]);
    }
#pragma unroll
    for (int i = 0; i < DF; ++i) {
      float x = ot[i];
      const float* w = W1 + (32 + i) * HF + ch * 16;
#pragma unroll
      for (int j = 0; j < 16; ++j) acc[j] = fmaf(x, w[j], acc[j]);
    }
    short8 s0, s1;
#pragma unroll
    for (int j = 0; j < 8; ++j) { s0[j] = (short)f2bf(acc[j]); s1[j] = (short)f2bf(acc[8+j]); }
    *(short8*)(abp + ch*16) = s0;
    *(short8*)(abp + ch*16 + 8) = s1;
  }
  // B half (at +64): xs rows 16..31, out rows 64..95
#pragma unroll 1
  for (int ch = 0; ch < 4; ++ch) {
    float acc[16];
#pragma unroll
    for (int j = 0; j < 16; ++j) acc[j] = 0.f;
#pragma unroll
    for (int i = 0; i < SF; ++i) {
      float x = xs[i];
      const float* w = W1 + (16 + i) * HF + ch * 16;
#pragma unroll
      for (int j = 0; j < 16; ++j) acc[j] = fmaf(x, w[j], acc[j]);
    }
#pragma unroll
    for (int i = 0; i < DF; ++i) {
      float x = ot[i];
      const float* w = W1 + (64 + i) * HF + ch * 16;
#pragma unroll
      for (int j = 0; j < 16; ++j) acc[j] = fmaf(x, w[j], acc[j]);
    }
    short8 s0, s1;
#pragma unroll
    for (int j = 0; j < 8; ++j) { s0[j] = (short)f2bf(acc[j]); s1[j] = (short)f2bf(acc[8+j]); }
    *(short8*)(abp + 64 + ch*16) = s0;
    *(short8*)(abp + 64 + ch*16 + 8) = s1;
  }
}

// ---------------- edge MLP (MFMA layer-2) + segmented reduce ----------------
__global__ __launch_bounds__(256, 4) void edge_kernel(
    const unsigned short* __restrict__ ABh, const unsigned short* __restrict__ outb,
    const float* __restrict__ sums, const unsigned short* __restrict__ ea_s,
    const int* __restrict__ row_s, const int* __restrict__ col_s,
    const float* __restrict__ W1, const float* __restrict__ b1,
    const float* __restrict__ W2, const float* __restrict__ b2,
    float* __restrict__ scattered) {
  __shared__ union { unsigned short h[256][72]; float sh[256][33]; } u;
  __shared__ int scol[256];
  __shared__ float msk[256];
  __shared__ unsigned short lst0[256], lst1[256];
  __shared__ int wbase[4];
  __shared__ int cnt;

  int tid = threadIdx.x;
  int bbase = blockIdx.x * 256;
  int i = bbase + tid;
  if (tid == 0) cnt = 0;
  int lcol = tid & 15;
  int kgrp = (tid >> 4) & 3;
  int wid = tid >> 6;

  // W2 B-fragments: lane holds col=lcol(+16*nt), k = kt*32 + kgrp*8 + q
  short8 w2f[2][2];
#pragma unroll
  for (int kt = 0; kt < 2; ++kt)
#pragma unroll
    for (int nt = 0; nt < 2; ++nt) {
#pragma unroll
      for (int q = 0; q < 8; ++q)
        w2f[kt][nt][q] = (short)f2bf(W2[(kt*32 + kgrp*8 + q) * DF + nt*16 + lcol]);
    }
  float b2c0 = b2[lcol], b2c1 = b2[16 + lcol];

  // ---- phase 1: build h (bf16) into LDS A-frag layout, 1 edge/lane ----
  if (i < NE) {
    int r = row_s[i];
    int c = col_s[i];
    scol[tid] = c;
    float s_r = sums[r], s_c = sums[c];
    msk[tid] = (s_r == 0.f && s_c == 0.f) ? 0.f : 1.f;
    float eav[8];
    {
      short8 ev = *(const short8*)(ea_s + (size_t)i * 8);
#pragma unroll
      for (int t = 0; t < 8; ++t) eav[t] = bf2f((unsigned short)ev[t]);
    }
    const unsigned short* ar = ABh + (size_t)r * 128;
    const unsigned short* bc = ABh + (size_t)c * 128 + 64;
#pragma unroll 1
    for (int ch = 0; ch < 4; ++ch) {
      short8 a0 = *(const short8*)(ar + ch*16);
      short8 a1 = *(const short8*)(ar + ch*16 + 8);
      short8 c0 = *(const short8*)(bc + ch*16);
      short8 c1 = *(const short8*)(bc + ch*16 + 8);
      short8 p0, p1;
#pragma unroll
      for (int j = 0; j < 16; ++j) {
        float cj = b1[ch*16 + j];
#pragma unroll
        for (int t = 0; t < 8; ++t)
          cj = fmaf(eav[t], W1[(96 + t) * HF + ch*16 + j], cj);
        float av = bf2f((unsigned short)(j < 8 ? a0[j] : a1[j-8]));
        float bv = bf2f((unsigned short)(j < 8 ? c0[j] : c1[j-8]));
        float hv = fmaxf(av + bv + cj, 0.f);
        unsigned short hb = f2bf(hv);
        if (j < 8) p0[j] = (short)hb; else p1[j-8] = (short)hb;
      }
      *(short8*)(&u.h[tid][ch*16]) = p0;
      *(short8*)(&u.h[tid][ch*16 + 8]) = p1;
    }
  } else {
    scol[tid] = -1;
    msk[tid] = 0.f;
  }
  __syncthreads();

  // ---- phase 2: MFMA over this wave's 4 groups of 16 edges ----
  floatx4 acc[4][2];
#pragma unroll
  for (int g = 0; g < 4; ++g) {
    int erow = wid*64 + g*16 + lcol;
    short8 a0 = *(const short8*)(&u.h[erow][kgrp*8]);
    short8 a1 = *(const short8*)(&u.h[erow][32 + kgrp*8]);
    floatx4 c0 = {b2c0, b2c0, b2c0, b2c0};
    floatx4 c1 = {b2c1, b2c1, b2c1, b2c1};
    c0 = __builtin_amdgcn_mfma_f32_16x16x32_bf16(a0, w2f[0][0], c0, 0, 0, 0);
    c0 = __builtin_amdgcn_mfma_f32_16x16x32_bf16(a1, w2f[1][0], c0, 0, 0, 0);
    c1 = __builtin_amdgcn_mfma_f32_16x16x32_bf16(a0, w2f[0][1], c1, 0, 0, 0);
    c1 = __builtin_amdgcn_mfma_f32_16x16x32_bf16(a1, w2f[1][1], c1, 0, 0, 0);
    acc[g][0] = c0;
    acc[g][1] = c1;
  }
  __syncthreads();  // all h reads done; sh (union) may be written now

  // ---- phase 3: norm + mask + shift, C-frag layout ----
#pragma unroll
  for (int g = 0; g < 4; ++g) {
    float nsq[4];
#pragma unroll
    for (int rr = 0; rr < 4; ++rr)
      nsq[rr] = acc[g][0][rr]*acc[g][0][rr] + acc[g][1][rr]*acc[g][1][rr];
#pragma unroll
    for (int mm = 1; mm <= 8; mm <<= 1) {
#pragma unroll
      for (int rr = 0; rr < 4; ++rr)
        nsq[rr] += __shfl_xor(nsq[rr], mm, 64);
    }
#pragma unroll
    for (int rr = 0; rr < 4; ++rr) {
      int e = wid*64 + g*16 + kgrp*4 + rr;
      if (bbase + e < NE) {
        float ms = (nsq[rr] > 0.f) ? rsqrtf(nsq[rr]) : 0.f;
        ms *= msk[e];
        int r2 = row_s[bbase + e];
        int c2 = scol[e];
        float ar0 = bf2f(outb[(size_t)r2*DF + lcol]);
        float ar1 = bf2f(outb[(size_t)r2*DF + 16 + lcol]);
        float bc0 = bf2f(outb[(size_t)c2*DF + lcol]);
        float bc1 = bf2f(outb[(size_t)c2*DF + 16 + lcol]);
        u.sh[e][lcol]      = (bc0 - ar0) * acc[g][0][rr] * ms;
        u.sh[e][16 + lcol] = (bc1 - ar1) * acc[g][1][rr] * ms;
      }
    }
  }
  __syncthreads();

  // ---- phase 4: segmented reduce over sorted-col runs ----
  int c_self = scol[tid];
  bool head = (c_self >= 0) && (tid == 0 || scol[tid-1] != c_self);
  unsigned long long m = __ballot(head);
  int lane = tid & 63;
  if (lane == 0) wbase[wid] = atomicAdd(&cnt, (int)__popcll(m));
  __syncthreads();
  if (head) {
    int idx = wbase[wid] + (int)__popcll(m & ((1ull << lane) - 1ull));
    int t1 = tid + 1;
    while (t1 < 256 && scol[t1] == c_self) ++t1;
    lst0[idx] = (unsigned short)tid;
    lst1[idx] = (unsigned short)t1;
  }
  __syncthreads();
  int nr = cnt;
  for (int task = tid; task < nr * 32; task += 256) {
    int rid = task >> 5, j = task & 31;
    int t0 = lst0[rid], t1 = lst1[rid];
    float s = 0.f;
    for (int t = t0; t < t1; ++t) s += u.sh[t][j];
    unsafeAtomicAdd(&scattered[(size_t)scol[t0] * DF + j], s);
  }
}

// ------- node update (in place): out += scattered @ Fk; scattered = 0 -------
__global__ __launch_bounds__(256) void node_kernel(
    float* __restrict__ out, float* __restrict__ scattered,
    const float* __restrict__ Fk) {
  int n = blockIdx.x * 256 + threadIdx.x;
  if (n >= NN) return;
  float s[DF];
  float4* sp = reinterpret_cast<float4*>(scattered + (size_t)n * DF);
#pragma unroll
  for (int q = 0; q < 8; ++q) {
    float4 v = sp[q];
    s[4*q+0]=v.x; s[4*q+1]=v.y; s[4*q+2]=v.z; s[4*q+3]=v.w;
  }
  float4* op = reinterpret_cast<float4*>(out + (size_t)n * DF);
#pragma unroll
  for (int q = 0; q < 8; ++q) {
    float4 acc = op[q];
#pragma unroll
    for (int i = 0; i < DF; ++i) {
      float si = s[i];
      acc.x = fmaf(si, Fk[i*DF + 4*q+0], acc.x);
      acc.y = fmaf(si, Fk[i*DF + 4*q+1], acc.y);
      acc.z = fmaf(si, Fk[i*DF + 4*q+2], acc.z);
      acc.w = fmaf(si, Fk[i*DF + 4*q+3], acc.w);
    }
    op[q] = acc;
  }
  float4 z = {0.f, 0.f, 0.f, 0.f};
#pragma unroll
  for (int q = 0; q < 8; ++q) sp[q] = z;
}

extern "C" void kernel_launch(void* const* d_in, const int* in_sizes, int n_in,
                              void* d_out, int out_size, void* d_ws, size_t ws_size,
                              hipStream_t stream) {
  const float* x_s = (const float*)d_in[0];
  const float* x_t = (const float*)d_in[1];
  const int*   ei  = (const int*)d_in[2];
  const float* ea  = (const float*)d_in[3];
  const float* W1  = (const float*)d_in[4];
  const float* b1  = (const float*)d_in[5];
  const float* W2  = (const float*)d_in[6];
  const float* b2  = (const float*)d_in[7];
  const float* F   = (const float*)d_in[8];

  float* out = (float*)d_out;
  char* ws = (char*)d_ws;
  float*          scattered = (float*)(ws);                       // 12.8 MB
  unsigned short* ABh       = (unsigned short*)(ws + 12800000);   // 25.6 MB
  unsigned short* outb      = (unsigned short*)(ws + 38400000);   // 6.4 MB
  float*          sums      = (float*)(ws + 44800000);            // 0.4 MB
  int*            row_s     = (int*)(ws + 45200000);              // 6.4 MB
  int*            col_s     = (int*)(ws + 51600000);              // 6.4 MB
  unsigned short* ea_s      = (unsigned short*)(ws + 58000000);   // 25.6 MB
  int*            deg       = (int*)(ws + 83600000);              // 0.4 MB
  int*            cur       = (int*)(ws + 84000000);              // 0.4 MB
  int*            bsums     = (int*)(ws + 84400000);              // 2 KB

  hipMemsetAsync(deg, 0, NN * sizeof(int), stream);
  hipMemsetAsync(scattered, 0, (size_t)NN * DF * sizeof(float), stream);

  dim3 blk(256);
  dim3 grid_e((NE + 255) / 256);
  dim3 grid_n((NN + 255) / 256);
  int nscan = (NN + 1023) / 1024;

  hist_kernel<<<grid_e, blk, 0, stream>>>(ei, deg);
  scan1_kernel<<<nscan, blk, 0, stream>>>(deg, cur, bsums);
  scan2_kernel<<<1, 1, 0, stream>>>(bsums, nscan);
  scan3_kernel<<<grid_n, blk, 0, stream>>>(cur, bsums);
  fill_kernel<<<grid_e, blk, 0, stream>>>(ei, ea, cur, row_s, col_s, ea_s);

  init_kernel<<<grid_n, blk, 0, stream>>>(x_t, F, out);

  for (int k = 0; k < 2; ++k) {
    pre_kernel<<<grid_n, blk, 0, stream>>>(x_s, out, W1, ABh, outb, sums);
    edge_kernel<<<grid_e, blk, 0, stream>>>(ABh, outb, sums, ea_s,
                                            row_s, col_s,
                                            W1, b1, W2, b2, scattered);
    node_kernel<<<grid_n, blk, 0, stream>>>(out, scattered,
                                            F + (size_t)(k + 1) * DF * DF);
  }
}

// Round 5
// 522.870 us; speedup vs baseline: 1.4356x; 1.4356x over previous
//
#include <hip/hip_runtime.h>

#define NN 100000
#define NE 1600000
#define SF 16
#define DF 32
#define EFT 8
#define HF 64

typedef __attribute__((ext_vector_type(8))) short short8;
typedef __attribute__((ext_vector_type(4))) float floatx4;

__device__ inline unsigned short f2bf(float f) {
  union { float f; unsigned int u; } v; v.f = f;
  unsigned int u = v.u + 0x7FFFu + ((v.u >> 16) & 1u);
  return (unsigned short)(u >> 16);
}
__device__ inline float bf2f(unsigned short h) {
  union { unsigned int u; float f; } v; v.u = ((unsigned int)h) << 16;
  return v.f;
}

// ---------------- CSR build ----------------
__global__ __launch_bounds__(256) void hist_kernel(const int* __restrict__ ei,
                                                   int* __restrict__ deg) {
  int e = blockIdx.x * 256 + threadIdx.x;
  if (e < NE) atomicAdd(&deg[ei[NE + e]], 1);
}

__global__ __launch_bounds__(256) void scan1_kernel(const int* __restrict__ deg,
                                                    int* __restrict__ cur,
                                                    int* __restrict__ bsums) {
  __shared__ int ts[256];
  int tid = threadIdx.x;
  int base = blockIdx.x * 1024 + tid * 4;
  int v[4];
#pragma unroll
  for (int q = 0; q < 4; ++q) v[q] = (base + q < NN) ? deg[base + q] : 0;
  int s = v[0] + v[1] + v[2] + v[3];
  ts[tid] = s;
  __syncthreads();
  for (int off = 1; off < 256; off <<= 1) {
    int t = (tid >= off) ? ts[tid - off] : 0;
    __syncthreads();
    ts[tid] += t;
    __syncthreads();
  }
  int excl = ts[tid] - s;
  if (tid == 255) bsums[blockIdx.x] = ts[255];
  int run = excl;
#pragma unroll
  for (int q = 0; q < 4; ++q) {
    if (base + q < NN) cur[base + q] = run;
    run += v[q];
  }
}

__global__ void scan2_kernel(int* __restrict__ bsums, int nb) {
  int acc = 0;
  for (int i = 0; i < nb; ++i) { int t = bsums[i]; bsums[i] = acc; acc += t; }
}

__global__ __launch_bounds__(256) void scan3_kernel(int* __restrict__ cur,
                                                    const int* __restrict__ bsums) {
  int i = blockIdx.x * 256 + threadIdx.x;
  if (i < NN) cur[i] += bsums[i >> 10];
}

__global__ __launch_bounds__(256) void fill_kernel(const int* __restrict__ ei,
                                                   const float* __restrict__ ea,
                                                   int* __restrict__ cur,
                                                   int* __restrict__ row_s,
                                                   int* __restrict__ col_s,
                                                   unsigned short* __restrict__ ea_s) {
  int e = blockIdx.x * 256 + threadIdx.x;
  if (e >= NE) return;
  int r = ei[e];
  int c = ei[NE + e];
  int pos = atomicAdd(&cur[c], 1);
  row_s[pos] = r;
  col_s[pos] = c;
  const float4* p = (const float4*)(ea + (size_t)e * EFT);
  float4 v0 = p[0], v1 = p[1];
  short8 ev;
  ev[0] = (short)f2bf(v0.x); ev[1] = (short)f2bf(v0.y);
  ev[2] = (short)f2bf(v0.z); ev[3] = (short)f2bf(v0.w);
  ev[4] = (short)f2bf(v1.x); ev[5] = (short)f2bf(v1.y);
  ev[6] = (short)f2bf(v1.z); ev[7] = (short)f2bf(v1.w);
  *(short8*)(ea_s + (size_t)pos * 8) = ev;
}

// ------- one-time: WpreT[col][k] (bf16, [128][64]) from W1 -------
// col<64  (A): k<16 -> W1[k][col];      16<=k<48 -> W1[32+(k-16)][col];  else 0
// col>=64 (B): k<16 -> W1[16+k][col-64];16<=k<48 -> W1[64+(k-16)][col-64];else 0
__global__ __launch_bounds__(256) void wpre_kernel(const float* __restrict__ W1,
                                                   unsigned short* __restrict__ WpreT) {
  int id = blockIdx.x * 256 + threadIdx.x;
  if (id >= 128 * 64) return;
  int col = id >> 6, k = id & 63;
  int j = col & 63;
  bool bh = col >= 64;
  float v = 0.f;
  if (k < 16) v = W1[((bh ? 16 : 0) + k) * HF + j];
  else if (k < 48) v = W1[((bh ? 64 : 32) + (k - 16)) * HF + j];
  WpreT[col * 64 + k] = f2bf(v);
}

// ---------------- init: out = x_t @ F[0]; also outb, sums ----------------
__global__ __launch_bounds__(256) void init_kernel(
    const float* __restrict__ x_t, const float* __restrict__ F0,
    float* __restrict__ out, unsigned short* __restrict__ outb,
    float* __restrict__ sums) {
  int n = blockIdx.x * 256 + threadIdx.x;
  if (n >= NN) return;
  float x[DF];
  const float4* xr = reinterpret_cast<const float4*>(x_t + (size_t)n * DF);
#pragma unroll
  for (int q = 0; q < 8; ++q) {
    float4 v = xr[q];
    x[4*q+0]=v.x; x[4*q+1]=v.y; x[4*q+2]=v.z; x[4*q+3]=v.w;
  }
  float4* orow = reinterpret_cast<float4*>(out + (size_t)n * DF);
  unsigned short* ob = outb + (size_t)n * DF;
  float s = 0.f;
#pragma unroll
  for (int q = 0; q < 8; ++q) {
    float4 acc = {0.f, 0.f, 0.f, 0.f};
#pragma unroll
    for (int i = 0; i < DF; ++i) {
      float xi = x[i];
      acc.x = fmaf(xi, F0[i*DF + 4*q+0], acc.x);
      acc.y = fmaf(xi, F0[i*DF + 4*q+1], acc.y);
      acc.z = fmaf(xi, F0[i*DF + 4*q+2], acc.z);
      acc.w = fmaf(xi, F0[i*DF + 4*q+3], acc.w);
    }
    orow[q] = acc;
    s += acc.x + acc.y + acc.z + acc.w;
    ushort4 pk = {f2bf(acc.x), f2bf(acc.y), f2bf(acc.z), f2bf(acc.w)};
    *(ushort4*)(ob + 4*q) = pk;
  }
  sums[n] = s;
}

// ------- pre (MFMA): ABh[n][128] = [xs(16)|out(32)|0(16)]bf16 @ Wpre -------
__global__ __launch_bounds__(256, 4) void pre_kernel(
    const float* __restrict__ x_s, const unsigned short* __restrict__ outb,
    const unsigned short* __restrict__ WpreT, unsigned short* __restrict__ ABh) {
  __shared__ unsigned short wlds[128][72];  // padded: 144B rows (16B-aligned)
  int tid = threadIdx.x;
  for (int t = tid; t < 128 * 8; t += 256) {
    int colr = t >> 3, kc = t & 7;
    short8 v = *(const short8*)(WpreT + colr * 64 + kc * 8);
    *(short8*)(&wlds[colr][kc * 8]) = v;
  }
  __syncthreads();

  int lcol = tid & 15, kgrp = (tid >> 4) & 3, wid = tid >> 6;
  int nodebase = blockIdx.x * 64 + wid * 16;
  int nodeA = nodebase + lcol;

  short8 a0 = {0,0,0,0,0,0,0,0}, a1 = {0,0,0,0,0,0,0,0};
  if (nodeA < NN) {
    const unsigned short* obp = outb + (size_t)nodeA * DF;
    if (kgrp == 0) {
      const float4* p = (const float4*)(x_s + (size_t)nodeA * SF);
      float4 v0 = p[0], v1 = p[1];
      a0[0]=(short)f2bf(v0.x); a0[1]=(short)f2bf(v0.y);
      a0[2]=(short)f2bf(v0.z); a0[3]=(short)f2bf(v0.w);
      a0[4]=(short)f2bf(v1.x); a0[5]=(short)f2bf(v1.y);
      a0[6]=(short)f2bf(v1.z); a0[7]=(short)f2bf(v1.w);
      a1 = *(const short8*)(obp + 16);
    } else if (kgrp == 1) {
      const float4* p = (const float4*)(x_s + (size_t)nodeA * SF);
      float4 v0 = p[2], v1 = p[3];
      a0[0]=(short)f2bf(v0.x); a0[1]=(short)f2bf(v0.y);
      a0[2]=(short)f2bf(v0.z); a0[3]=(short)f2bf(v0.w);
      a0[4]=(short)f2bf(v1.x); a0[5]=(short)f2bf(v1.y);
      a0[6]=(short)f2bf(v1.z); a0[7]=(short)f2bf(v1.w);
      a1 = *(const short8*)(obp + 24);
    } else if (kgrp == 2) {
      a0 = *(const short8*)(obp + 0);
    } else {
      a0 = *(const short8*)(obp + 8);
    }
  }

  floatx4 acc[8];
#pragma unroll
  for (int nt = 0; nt < 8; ++nt) {
    short8 b0 = *(const short8*)(&wlds[nt * 16 + lcol][kgrp * 8]);
    short8 b1 = *(const short8*)(&wlds[nt * 16 + lcol][32 + kgrp * 8]);
    floatx4 c = {0.f, 0.f, 0.f, 0.f};
    c = __builtin_amdgcn_mfma_f32_16x16x32_bf16(a0, b0, c, 0, 0, 0);
    c = __builtin_amdgcn_mfma_f32_16x16x32_bf16(a1, b1, c, 0, 0, 0);
    acc[nt] = c;
  }

#pragma unroll
  for (int rr = 0; rr < 4; ++rr) {
    int node = nodebase + kgrp * 4 + rr;
    if (node < NN) {
      unsigned short* dst = ABh + (size_t)node * 128;
#pragma unroll
      for (int nt = 0; nt < 8; ++nt)
        dst[nt * 16 + lcol] = f2bf(acc[nt][rr]);
    }
  }
}

// ---------------- edge MLP (MFMA layer-2) + segmented reduce ----------------
__global__ __launch_bounds__(256, 4) void edge_kernel(
    const unsigned short* __restrict__ ABh, const unsigned short* __restrict__ outb,
    const float* __restrict__ sums, const unsigned short* __restrict__ ea_s,
    const int* __restrict__ row_s, const int* __restrict__ col_s,
    const float* __restrict__ W1, const float* __restrict__ b1,
    const float* __restrict__ W2, const float* __restrict__ b2,
    float* __restrict__ scattered) {
  __shared__ union { unsigned short h[256][72]; float sh[256][33]; } u;
  __shared__ int scol[256];
  __shared__ int srow[256];
  __shared__ union { float msk[256]; struct { unsigned short l0[256], l1[256]; } seg; } vv;
  __shared__ int wbase[4];
  __shared__ int cnt;

  int tid = threadIdx.x;
  int bbase = blockIdx.x * 256;
  int i = bbase + tid;
  if (tid == 0) cnt = 0;
  int lcol = tid & 15;
  int kgrp = (tid >> 4) & 3;
  int wid = tid >> 6;

  // W2 B-fragments: lane holds col=lcol(+16*nt), k = kt*32 + kgrp*8 + q
  short8 w2f[2][2];
#pragma unroll
  for (int kt = 0; kt < 2; ++kt)
#pragma unroll
    for (int nt = 0; nt < 2; ++nt) {
#pragma unroll
      for (int q = 0; q < 8; ++q)
        w2f[kt][nt][q] = (short)f2bf(W2[(kt*32 + kgrp*8 + q) * DF + nt*16 + lcol]);
    }
  float b2c0 = b2[lcol], b2c1 = b2[16 + lcol];

  // ---- phase 1: build h (bf16) into LDS A-frag layout, 1 edge/lane ----
  if (i < NE) {
    int r = row_s[i];
    int c = col_s[i];
    scol[tid] = c;
    srow[tid] = r;
    float s_r = sums[r], s_c = sums[c];
    vv.msk[tid] = (s_r == 0.f && s_c == 0.f) ? 0.f : 1.f;
    float eav[8];
    {
      short8 ev = *(const short8*)(ea_s + (size_t)i * 8);
#pragma unroll
      for (int t = 0; t < 8; ++t) eav[t] = bf2f((unsigned short)ev[t]);
    }
    const unsigned short* ar = ABh + (size_t)r * 128;
    const unsigned short* bc = ABh + (size_t)c * 128 + 64;
#pragma unroll 1
    for (int ch = 0; ch < 4; ++ch) {
      short8 a0 = *(const short8*)(ar + ch*16);
      short8 a1 = *(const short8*)(ar + ch*16 + 8);
      short8 c0 = *(const short8*)(bc + ch*16);
      short8 c1 = *(const short8*)(bc + ch*16 + 8);
      short8 p0, p1;
#pragma unroll
      for (int j = 0; j < 16; ++j) {
        float cj = b1[ch*16 + j];
#pragma unroll
        for (int t = 0; t < 8; ++t)
          cj = fmaf(eav[t], W1[(96 + t) * HF + ch*16 + j], cj);
        float av = bf2f((unsigned short)(j < 8 ? a0[j] : a1[j-8]));
        float bv = bf2f((unsigned short)(j < 8 ? c0[j] : c1[j-8]));
        float hv = fmaxf(av + bv + cj, 0.f);
        unsigned short hb = f2bf(hv);
        if (j < 8) p0[j] = (short)hb; else p1[j-8] = (short)hb;
      }
      *(short8*)(&u.h[tid][ch*16]) = p0;
      *(short8*)(&u.h[tid][ch*16 + 8]) = p1;
    }
  } else {
    scol[tid] = -1;
    srow[tid] = 0;
    vv.msk[tid] = 0.f;
  }
  __syncthreads();

  // ---- phase 2: MFMA over this wave's 4 groups of 16 edges ----
  floatx4 acc[4][2];
#pragma unroll
  for (int g = 0; g < 4; ++g) {
    int erow = wid*64 + g*16 + lcol;
    short8 a0 = *(const short8*)(&u.h[erow][kgrp*8]);
    short8 a1 = *(const short8*)(&u.h[erow][32 + kgrp*8]);
    floatx4 c0 = {b2c0, b2c0, b2c0, b2c0};
    floatx4 c1 = {b2c1, b2c1, b2c1, b2c1};
    c0 = __builtin_amdgcn_mfma_f32_16x16x32_bf16(a0, w2f[0][0], c0, 0, 0, 0);
    c0 = __builtin_amdgcn_mfma_f32_16x16x32_bf16(a1, w2f[1][0], c0, 0, 0, 0);
    c1 = __builtin_amdgcn_mfma_f32_16x16x32_bf16(a0, w2f[0][1], c1, 0, 0, 0);
    c1 = __builtin_amdgcn_mfma_f32_16x16x32_bf16(a1, w2f[1][1], c1, 0, 0, 0);
    acc[g][0] = c0;
    acc[g][1] = c1;
  }
  __syncthreads();  // all h reads done; sh (union) may be written now

  // ---- phase 3: norm + mask + shift, C-frag layout ----
#pragma unroll
  for (int g = 0; g < 4; ++g) {
    float nsq[4];
#pragma unroll
    for (int rr = 0; rr < 4; ++rr)
      nsq[rr] = acc[g][0][rr]*acc[g][0][rr] + acc[g][1][rr]*acc[g][1][rr];
#pragma unroll
    for (int mm = 1; mm <= 8; mm <<= 1) {
#pragma unroll
      for (int rr = 0; rr < 4; ++rr)
        nsq[rr] += __shfl_xor(nsq[rr], mm, 64);
    }
#pragma unroll
    for (int rr = 0; rr < 4; ++rr) {
      int e = wid*64 + g*16 + kgrp*4 + rr;
      if (bbase + e < NE) {
        float ms = (nsq[rr] > 0.f) ? rsqrtf(nsq[rr]) : 0.f;
        ms *= vv.msk[e];
        int r2 = srow[e];
        int c2 = scol[e];
        float ar0 = bf2f(outb[(size_t)r2*DF + lcol]);
        float ar1 = bf2f(outb[(size_t)r2*DF + 16 + lcol]);
        float bc0 = bf2f(outb[(size_t)c2*DF + lcol]);
        float bc1 = bf2f(outb[(size_t)c2*DF + 16 + lcol]);
        u.sh[e][lcol]      = (bc0 - ar0) * acc[g][0][rr] * ms;
        u.sh[e][16 + lcol] = (bc1 - ar1) * acc[g][1][rr] * ms;
      }
    }
  }
  __syncthreads();

  // ---- phase 4: segmented reduce over sorted-col runs ----
  int c_self = scol[tid];
  bool head = (c_self >= 0) && (tid == 0 || scol[tid-1] != c_self);
  unsigned long long m = __ballot(head);
  int lane = tid & 63;
  if (lane == 0) wbase[wid] = atomicAdd(&cnt, (int)__popcll(m));
  __syncthreads();
  if (head) {
    int idx = wbase[wid] + (int)__popcll(m & ((1ull << lane) - 1ull));
    int t1 = tid + 1;
    while (t1 < 256 && scol[t1] == c_self) ++t1;
    vv.seg.l0[idx] = (unsigned short)tid;
    vv.seg.l1[idx] = (unsigned short)t1;
  }
  __syncthreads();
  int nr = cnt;
  for (int task = tid; task < nr * 32; task += 256) {
    int rid = task >> 5, j = task & 31;
    int t0 = vv.seg.l0[rid], t1 = vv.seg.l1[rid];
    float s = 0.f;
    for (int t = t0; t < t1; ++t) s += u.sh[t][j];
    unsafeAtomicAdd(&scattered[(size_t)scol[t0] * DF + j], s);
  }
}

// --- node update (in place): out += scattered @ Fk; outb/sums; clear sc ---
__global__ __launch_bounds__(256) void node_kernel(
    float* __restrict__ out, float* __restrict__ scattered,
    const float* __restrict__ Fk, unsigned short* __restrict__ outb,
    float* __restrict__ sums) {
  int n = blockIdx.x * 256 + threadIdx.x;
  if (n >= NN) return;
  float s[DF];
  float4* sp = reinterpret_cast<float4*>(scattered + (size_t)n * DF);
#pragma unroll
  for (int q = 0; q < 8; ++q) {
    float4 v = sp[q];
    s[4*q+0]=v.x; s[4*q+1]=v.y; s[4*q+2]=v.z; s[4*q+3]=v.w;
  }
  float4* op = reinterpret_cast<float4*>(out + (size_t)n * DF);
  unsigned short* ob = outb + (size_t)n * DF;
  float ssum = 0.f;
#pragma unroll
  for (int q = 0; q < 8; ++q) {
    float4 acc = op[q];
#pragma unroll
    for (int i = 0; i < DF; ++i) {
      float si = s[i];
      acc.x = fmaf(si, Fk[i*DF + 4*q+0], acc.x);
      acc.y = fmaf(si, Fk[i*DF + 4*q+1], acc.y);
      acc.z = fmaf(si, Fk[i*DF + 4*q+2], acc.z);
      acc.w = fmaf(si, Fk[i*DF + 4*q+3], acc.w);
    }
    op[q] = acc;
    ssum += acc.x + acc.y + acc.z + acc.w;
    ushort4 pk = {f2bf(acc.x), f2bf(acc.y), f2bf(acc.z), f2bf(acc.w)};
    *(ushort4*)(ob + 4*q) = pk;
  }
  sums[n] = ssum;
  float4 z = {0.f, 0.f, 0.f, 0.f};
#pragma unroll
  for (int q = 0; q < 8; ++q) sp[q] = z;
}

extern "C" void kernel_launch(void* const* d_in, const int* in_sizes, int n_in,
                              void* d_out, int out_size, void* d_ws, size_t ws_size,
                              hipStream_t stream) {
  const float* x_s = (const float*)d_in[0];
  const float* x_t = (const float*)d_in[1];
  const int*   ei  = (const int*)d_in[2];
  const float* ea  = (const float*)d_in[3];
  const float* W1  = (const float*)d_in[4];
  const float* b1  = (const float*)d_in[5];
  const float* W2  = (const float*)d_in[6];
  const float* b2  = (const float*)d_in[7];
  const float* F   = (const float*)d_in[8];

  float* out = (float*)d_out;
  char* ws = (char*)d_ws;
  float*          scattered = (float*)(ws);                       // 12.8 MB
  unsigned short* ABh       = (unsigned short*)(ws + 12800000);   // 25.6 MB
  unsigned short* outb      = (unsigned short*)(ws + 38400000);   // 6.4 MB
  float*          sums      = (float*)(ws + 44800000);            // 0.4 MB
  int*            row_s     = (int*)(ws + 45200000);              // 6.4 MB
  int*            col_s     = (int*)(ws + 51600000);              // 6.4 MB
  unsigned short* ea_s      = (unsigned short*)(ws + 58000000);   // 25.6 MB
  int*            deg       = (int*)(ws + 83600000);              // 0.4 MB
  int*            cur       = (int*)(ws + 84000000);              // 0.4 MB
  int*            bsums     = (int*)(ws + 84400000);              // <1 KB
  unsigned short* WpreT     = (unsigned short*)(ws + 84401024);   // 16 KB

  hipMemsetAsync(deg, 0, NN * sizeof(int), stream);
  hipMemsetAsync(scattered, 0, (size_t)NN * DF * sizeof(float), stream);

  dim3 blk(256);
  dim3 grid_e((NE + 255) / 256);
  dim3 grid_n((NN + 255) / 256);
  dim3 grid_p((NN + 63) / 64);
  int nscan = (NN + 1023) / 1024;

  hist_kernel<<<grid_e, blk, 0, stream>>>(ei, deg);
  scan1_kernel<<<nscan, blk, 0, stream>>>(deg, cur, bsums);
  scan2_kernel<<<1, 1, 0, stream>>>(bsums, nscan);
  scan3_kernel<<<grid_n, blk, 0, stream>>>(cur, bsums);
  fill_kernel<<<grid_e, blk, 0, stream>>>(ei, ea, cur, row_s, col_s, ea_s);
  wpre_kernel<<<32, blk, 0, stream>>>(W1, WpreT);

  init_kernel<<<grid_n, blk, 0, stream>>>(x_t, F, out, outb, sums);

  for (int k = 0; k < 2; ++k) {
    pre_kernel<<<grid_p, blk, 0, stream>>>(x_s, outb, WpreT, ABh);
    edge_kernel<<<grid_e, blk, 0, stream>>>(ABh, outb, sums, ea_s,
                                            row_s, col_s,
                                            W1, b1, W2, b2, scattered);
    node_kernel<<<grid_n, blk, 0, stream>>>(out, scattered,
                                            F + (size_t)(k + 1) * DF * DF,
                                            outb, sums);
  }
}